// Round 12
// baseline (3809.955 us; speedup 1.0000x reference)
//
#include <hip/hip_runtime.h>

#define B_ 128
#define T_ 80
#define AD 32
#define ZD 64
#define KD 16
#define S8 68   // stride for 64-col LDS matrices (16B-aligned rows)
#define SC 36   // stride for 32-col matrices (16B-aligned rows)

__device__ __forceinline__ float4 ld4(const float* p) { return *(const float4*)p; }
__device__ __forceinline__ void st4f(float* p, float4 v) { *(float4*)p = v; }
__device__ __forceinline__ float4 sub4(float4 a, float4 b) {
    return make_float4(a.x - b.x, a.y - b.y, a.z - b.z, a.w - b.w);
}
// row-vector c times matrix given as rows x0..x3
__device__ __forceinline__ float4 comb4(float4 c, float4 x0, float4 x1, float4 x2, float4 x3) {
    return make_float4(c.x*x0.x + c.y*x1.x + c.z*x2.x + c.w*x3.x,
                       c.x*x0.y + c.y*x1.y + c.z*x2.y + c.w*x3.y,
                       c.x*x0.z + c.y*x1.z + c.z*x2.z + c.w*x3.z,
                       c.x*x0.w + c.y*x1.w + c.z*x2.w + c.w*x3.w);
}

// 4x4 inverse via 2x2-block Schur (SPD -> no pivoting). Returns rows of the inverse.
__device__ __forceinline__ void pinv4(float4 q0, float4 q1, float4 q2, float4 q3,
                                      float4& pi0, float4& pi1, float4& pi2, float4& pi3)
{
    const float ra = 1.0f / (q0.x*q1.y - q0.y*q1.x);
    const float ai00 =  q1.y*ra, ai01 = -q0.y*ra, ai10 = -q1.x*ra, ai11 = q0.x*ra;
    const float ca00 = q2.x*ai00 + q2.y*ai10, ca01 = q2.x*ai01 + q2.y*ai11;
    const float ca10 = q3.x*ai00 + q3.y*ai10, ca11 = q3.x*ai01 + q3.y*ai11;
    const float s00 = q2.z - (ca00*q0.z + ca01*q1.z), s01 = q2.w - (ca00*q0.w + ca01*q1.w);
    const float s10 = q3.z - (ca10*q0.z + ca11*q1.z), s11 = q3.w - (ca10*q0.w + ca11*q1.w);
    const float rs = 1.0f / (s00*s11 - s01*s10);
    const float si00 = s11*rs, si01 = -s01*rs, si10 = -s10*rs, si11 = s00*rs;
    const float ab00 = ai00*q0.z + ai01*q1.z, ab01 = ai00*q0.w + ai01*q1.w;
    const float ab10 = ai10*q0.z + ai11*q1.z, ab11 = ai10*q0.w + ai11*q1.w;
    const float t00 = ab00*si00 + ab01*si10, t01 = ab00*si01 + ab01*si11;
    const float t10 = ab10*si00 + ab11*si10, t11 = ab10*si01 + ab11*si11;
    const float tl00 = ai00 + (t00*ca00 + t01*ca10), tl01 = ai01 + (t00*ca01 + t01*ca11);
    const float tl10 = ai10 + (t10*ca00 + t11*ca10), tl11 = ai11 + (t10*ca01 + t11*ca11);
    const float bl00 = -(si00*ca00 + si01*ca10), bl01 = -(si00*ca01 + si01*ca11);
    const float bl10 = -(si10*ca00 + si11*ca10), bl11 = -(si10*ca01 + si11*ca11);
    pi0 = make_float4(tl00, tl01, -t00, -t01);
    pi1 = make_float4(tl10, tl11, -t10, -t11);
    pi2 = make_float4(bl00, bl01, si00, si01);
    pi3 = make_float4(bl10, bl11, si10, si11);
}

// acc[2][4] += op(Pa) @ Qb for rows (r2,r2+1), cols c4..c4+3.
template<int KL, int AS, int BS, bool ATRANS>
__device__ __forceinline__ void mm64(const float* __restrict__ Pa, const float* __restrict__ Qb,
                                     float acc[2][4], int r2, int c4)
{
#pragma unroll 8
    for (int k = 0; k < KL; k++) {
        float aA, aB;
        if (ATRANS) { aA = Pa[k * AS + r2];   aB = Pa[k * AS + r2 + 1]; }
        else        { aA = Pa[r2 * AS + k];   aB = Pa[(r2 + 1) * AS + k]; }
        const float4 bv = ld4(&Qb[k * BS + c4]);
        acc[0][0] += aA * bv.x; acc[0][1] += aA * bv.y; acc[0][2] += aA * bv.z; acc[0][3] += aA * bv.w;
        acc[1][0] += aB * bv.x; acc[1][1] += aB * bv.y; acc[1][2] += aB * bv.z; acc[1][3] += aB * bv.w;
    }
}

// acc[4][4] += op(Pa) @ Qb for rows r4..r4+3, cols c4..c4+3 (fat tile, 256 threads).
// ATRANS reads A column-slices as contiguous f4; row-major reads merge across unrolled k.
template<int KL, int AS, int BS, bool ATRANS>
__device__ __forceinline__ void mm44(const float* __restrict__ Pa, const float* __restrict__ Qb,
                                     float acc[4][4], int r4, int c4)
{
#pragma unroll 4
    for (int k = 0; k < KL; k++) {
        float a0, a1, a2, a3;
        if (ATRANS) {
            const float4 av = ld4(&Pa[k * AS + r4]);
            a0 = av.x; a1 = av.y; a2 = av.z; a3 = av.w;
        } else {
            a0 = Pa[(r4 + 0) * AS + k]; a1 = Pa[(r4 + 1) * AS + k];
            a2 = Pa[(r4 + 2) * AS + k]; a3 = Pa[(r4 + 3) * AS + k];
        }
        const float4 bv = ld4(&Qb[k * BS + c4]);
        acc[0][0] += a0 * bv.x; acc[0][1] += a0 * bv.y; acc[0][2] += a0 * bv.z; acc[0][3] += a0 * bv.w;
        acc[1][0] += a1 * bv.x; acc[1][1] += a1 * bv.y; acc[1][2] += a1 * bv.z; acc[1][3] += a1 * bv.w;
        acc[2][0] += a2 * bv.x; acc[2][1] += a2 * bv.y; acc[2][2] += a2 * bv.z; acc[2][3] += a2 * bv.w;
        acc[3][0] += a3 * bv.x; acc[3][1] += a3 * bv.y; acc[3][2] += a3 * bv.z; acc[3][3] += a3 * bv.w;
    }
}

__global__ __launch_bounds__(512, 2)
void kvae_kernel(const float* __restrict__ obs, const float* __restrict__ logits,
                 const float* __restrict__ AK, const float* __restrict__ CK,
                 float* __restrict__ out)
{
    __shared__ __align__(16) float W[T_ * KD];
    __shared__ __align__(16) float Am[ZD * S8];   // A(t+1)
    __shared__ __align__(16) float At[ZD * S8];   // A(t+1)^T
    __shared__ __align__(16) float SP[ZD * S8];   // sig_p / spn / V
    __shared__ __align__(16) float SF[ZD * S8];   // sig_f
    __shared__ __align__(16) float Mm[ZD * S8];   // M
    __shared__ __align__(16) float Pool[9984];
    __shared__ __align__(16) float pvL[512];      // published pivot rows, left
    __shared__ __align__(16) float pvR[512];      // published pivot rows, right
    __shared__ __align__(16) float fbb[512];      // per-row multiplier quads
    __shared__ __align__(16) float pvE[8];        // err col pivot values [2][4]
    __shared__ __align__(16) float y_s[32];
    __shared__ __align__(16) float errv[32];
    __shared__ __align__(16) float uev[32];
    __shared__ __align__(16) float mup[64];
    __shared__ __align__(16) float muf[64];
    __shared__ __align__(16) float mus[64];
    __shared__ __align__(16) float mpn[64];
    __shared__ __align__(16) float dv[64];

    // forward aliases
    float* T1 = Pool;            // [32][68]
    float* CM = Pool + 2176;     // [32][68]
    float* CT = Pool + 4352;     // [64][36]  C^T
    float* U_ = Pool + 6656;     // [32][68]  S^-1 T1
    float* S_ = Pool + 8832;     // [32][36]
    // backward aliases
    float* Xb = Pool;            // [64][68]  X = spn^-1 M
    float* SG = Pool + 4352;     // [64][68]  sig_s carry

    const int tid = threadIdx.x;
    const int b   = blockIdx.x;

    const int r16 = tid >> 4;       // 0..31
    const int cg  = tid & 15;       // 0..15
    const int c4  = cg << 2;        // 0..60
    const int c2  = cg << 1;        // 0..30
    const int r2  = r16 << 1;       // 0..62
    const int gi  = tid >> 3;       // 0..63  GJ64 row
    const int gs  = tid & 7;        // 0..7   GJ64 seg (8 cols)
    const int r4f = (tid & 255) >> 4 << 2;  // 0..60 fat-tile rows (tid<256)
    const int r2h = (tid & 255) >> 4 << 1;  // 0..30 fat s1 rows (tid<256)

    const float* obs_b = obs    + (size_t)b * T_ * AD;
    const float* lg_b  = logits + (size_t)b * T_ * KD;
    float* omu = out + (size_t)b * T_ * ZD;
    float* osg = out + (size_t)B_ * T_ * ZD + (size_t)b * T_ * ZD * ZD;
    const float4* AK4 = (const float4*)AK;
    const float4* CK4 = (const float4*)CK;

    auto mixA = [&](int tt) {
#pragma unroll
        for (int rr = 0; rr < 2; rr++) {
            const int r = r2 + rr;
            float4 a = make_float4(0.f, 0.f, 0.f, 0.f);
#pragma unroll
            for (int k = 0; k < KD; k++) {
                const float wk = W[tt * KD + k];
                const float4 v = AK4[k * 1024 + r * 16 + cg];
                a.x += wk * v.x; a.y += wk * v.y; a.z += wk * v.z; a.w += wk * v.w;
            }
            st4f(&Am[r * S8 + c4], a);
            At[(c4 + 0) * S8 + r] = a.x; At[(c4 + 1) * S8 + r] = a.y;
            At[(c4 + 2) * S8 + r] = a.z; At[(c4 + 3) * S8 + r] = a.w;
        }
    };
    auto mixC = [&](int tt) {
        float4 a = make_float4(0.f, 0.f, 0.f, 0.f);
#pragma unroll
        for (int k = 0; k < KD; k++) {
            const float wk = W[tt * KD + k];
            const float4 v = CK4[k * 512 + r16 * 16 + cg];
            a.x += wk * v.x; a.y += wk * v.y; a.z += wk * v.z; a.w += wk * v.w;
        }
        st4f(&CM[r16 * S8 + c4], a);
        CT[(c4 + 0) * SC + r16] = a.x; CT[(c4 + 1) * SC + r16] = a.y;
        CT[(c4 + 2) * SC + r16] = a.z; CT[(c4 + 3) * SC + r16] = a.w;
    };

    // ---- prologue
    if (tid < T_) {
        float l[KD]; float mx = -1e30f;
#pragma unroll
        for (int k = 0; k < KD; k++) { l[k] = lg_b[tid * KD + k]; mx = fmaxf(mx, l[k]); }
        float s = 0.f;
#pragma unroll
        for (int k = 0; k < KD; k++) { l[k] = expf(l[k] - mx); s += l[k]; }
        const float inv = 1.0f / s;
#pragma unroll
        for (int k = 0; k < KD; k++) W[tid * KD + k] = l[k] * inv;
    }
#pragma unroll
    for (int rr = 0; rr < 2; rr++) {
        const int r = r2 + rr;
#pragma unroll
        for (int j = 0; j < 4; j++) SP[r * S8 + c4 + j] = (r == c4 + j) ? 20.0f : 0.0f;
    }
    if (tid < ZD) mup[tid] = 0.0f;
    __syncthreads();

    // ================= FORWARD FILTER =================
    for (int t = 0; t < T_; t++) {
        // s0: mix A(t+1), C(t); load y
        if (t < T_ - 1) mixA(t + 1);
        mixC(t);
        if (tid < AD) y_s[tid] = obs_b[t * AD + tid];
        __syncthreads();

        // s1: T1 = CM @ SP  [32x64] k=64  (fat: 256 threads, 2x4)
        if (tid < 256) {
            float acc[2][4] = {};
            mm64<ZD, S8, S8, false>(CM, SP, acc, r2h, c4);
#pragma unroll
            for (int rr = 0; rr < 2; rr++)
                st4f(&T1[(r2h + rr) * S8 + c4],
                     make_float4(acc[rr][0], acc[rr][1], acc[rr][2], acc[rr][3]));
        }
        __syncthreads();

        // s2: S = T1 @ CT + 0.03 I ; errv = y - CM @ mup   (512-wide)
        {
            float a0 = 0, a1 = 0;
            const float* pa = T1 + r16 * S8;
#pragma unroll 8
            for (int k = 0; k < ZD; k++) {
                const float a = pa[k];
                const float2 bv = *(const float2*)&CT[k * SC + c2];
                a0 += a * bv.x; a1 += a * bv.y;
            }
            if (r16 == c2)     a0 += 0.03f;
            if (r16 == c2 + 1) a1 += 0.03f;
            S_[r16 * SC + c2] = a0; S_[r16 * SC + c2 + 1] = a1;
        }
        if (tid < AD) {
            float s = 0.f;
#pragma unroll
            for (int k4 = 0; k4 < ZD; k4 += 4) {
                const float4 cm = ld4(&CM[tid * S8 + k4]);
                const float4 mu = ld4(&mup[k4]);
                s += cm.x*mu.x + cm.y*mu.y + cm.z*mu.z + cm.w*mu.w;
            }
            errv[tid] = y_s[tid] - s;
        }
        __syncthreads();

        // ---- GJ32 (4-wide pivots, 8 steps): [S_ | T1, errv] -> U_, uev
        {
            const int hi = r16, hs = cg;
            float4 aL = make_float4(0, 0, 0, 0);
            float4 aR = ld4(&T1[hi * S8 + hs * 4]);
            float e = 0.f;
            if (hs < 8) aL = ld4(&S_[hi * SC + hs * 4]);
            if (hs == 15) e = errv[hi];
            if (hi < 4) {
                if (hs < 8) st4f(&pvL[hi * 32 + hs * 4], aL);        // pvL fwd: [2][4][32]
                st4f(&pvR[hi * 64 + hs * 4], aR);
                if (hs == 15) pvE[hi] = e;
            }
            if (hs == 0) st4f(&fbb[hi * 4], aL);                     // fbb fwd: [2][32][4]
            __syncthreads();

#pragma unroll 2
            for (int j = 0; j < 8; ++j) {
                const int par = j & 1, nb = par ^ 1;
                const bool isp = (hi >> 2) == j;
                const int i4 = hi & 3;
                const float4 q0 = ld4(&fbb[par * 128 + (4 * j + 0) * 4]);
                const float4 q1 = ld4(&fbb[par * 128 + (4 * j + 1) * 4]);
                const float4 q2 = ld4(&fbb[par * 128 + (4 * j + 2) * 4]);
                const float4 q3 = ld4(&fbb[par * 128 + (4 * j + 3) * 4]);
                float4 pi0, pi1, pi2, pi3;
                pinv4(q0, q1, q2, q3, pi0, pi1, pi2, pi3);
                float4 coef;
                if (isp) coef = (i4 == 0 ? pi0 : i4 == 1 ? pi1 : i4 == 2 ? pi2 : pi3);
                else {
                    const float4 f = ld4(&fbb[par * 128 + hi * 4]);
                    coef = comb4(f, pi0, pi1, pi2, pi3);
                }
                // right (always live)
                {
                    const float4 c = comb4(coef,
                        ld4(&pvR[par * 256 + 0 * 64 + hs * 4]),
                        ld4(&pvR[par * 256 + 1 * 64 + hs * 4]),
                        ld4(&pvR[par * 256 + 2 * 64 + hs * 4]),
                        ld4(&pvR[par * 256 + 3 * 64 + hs * 4]));
                    if (isp) aR = c; else aR = sub4(aR, c);
                }
                // left
                if (hs < 8) {
                    const float4 c = comb4(coef,
                        ld4(&pvL[par * 128 + 0 * 32 + hs * 4]),
                        ld4(&pvL[par * 128 + 1 * 32 + hs * 4]),
                        ld4(&pvL[par * 128 + 2 * 32 + hs * 4]),
                        ld4(&pvL[par * 128 + 3 * 32 + hs * 4]));
                    if (isp) aL = c; else aL = sub4(aL, c);
                }
                // err
                if (hs == 15) {
                    const float4 ev = ld4(&pvE[par * 4]);
                    const float ce = coef.x*ev.x + coef.y*ev.y + coef.z*ev.z + coef.w*ev.w;
                    if (isp) e = ce; else e -= ce;
                }
                if (j < 7) {
                    if ((hi >> 2) == j + 1) {   // publish next pivot rows
                        if (hs < 8) st4f(&pvL[nb * 128 + i4 * 32 + hs * 4], aL);
                        st4f(&pvR[nb * 256 + i4 * 64 + hs * 4], aR);
                        if (hs == 15) pvE[nb * 4 + i4] = e;
                    }
                    if (hs == j + 1) st4f(&fbb[nb * 128 + hi * 4], aL);
                }
                __syncthreads();
            }
            st4f(&U_[hi * S8 + hs * 4], aR);
            if (hs == 15) uev[hi] = e;
        }
        __syncthreads();

        // s3: sig_f = SP - T1^T U_ -> SF & out (fat) ; mu_f = mup + T1^T uev (wave 7)
        if (tid < 256) {
            float acc[4][4] = {};
            mm44<AD, S8, S8, true>(T1, U_, acc, r4f, c4);
            float* og = osg + (size_t)t * ZD * ZD;
#pragma unroll
            for (int q = 0; q < 4; q++) {
                const int r = r4f + q;
                const float4 sp = ld4(&SP[r * S8 + c4]);
                const float4 v = make_float4(sp.x - acc[q][0], sp.y - acc[q][1],
                                             sp.z - acc[q][2], sp.w - acc[q][3]);
                st4f(&SF[r * S8 + c4], v);
                *(float4*)(og + r * ZD + c4) = v;
            }
        }
        if (tid >= 448) {
            const int i = tid - 448;
            float s = 0.f;
#pragma unroll
            for (int k = 0; k < AD; k++) s += T1[k * S8 + i] * uev[k];
            const float v = mup[i] + s;
            muf[i] = v;
            omu[t * ZD + i] = v;
        }
        __syncthreads();

        if (t < T_ - 1) {
            // s4: M = A(t+1) @ SF (fat)
            if (tid < 256) {
                float acc[4][4] = {};
                mm44<ZD, S8, S8, false>(Am, SF, acc, r4f, c4);
#pragma unroll
                for (int q = 0; q < 4; q++)
                    st4f(&Mm[(r4f + q) * S8 + c4],
                         make_float4(acc[q][0], acc[q][1], acc[q][2], acc[q][3]));
            }
            __syncthreads();
            // s5: SP' = M @ A^T + Q (fat) ; mup' = A(t+1) @ muf (wave 7)
            if (tid < 256) {
                float acc[4][4] = {};
                mm44<ZD, S8, S8, false>(Mm, At, acc, r4f, c4);
#pragma unroll
                for (int q = 0; q < 4; q++) {
                    const int r = r4f + q;
#pragma unroll
                    for (int j = 0; j < 4; j++)
                        SP[r * S8 + c4 + j] = acc[q][j] + ((r == c4 + j) ? 0.08f : 0.0f);
                }
            }
            if (tid >= 448) {
                const int i = tid - 448;
                float s = 0.f;
                const float* pa = Am + i * S8;
#pragma unroll 8
                for (int k = 0; k < ZD; k++) s += pa[k] * muf[k];
                mup[i] = s;
            }
            __syncthreads();
        }
    }

    // ================= SMOOTHER INIT =================
#pragma unroll
    for (int rr = 0; rr < 2; rr++)
        st4f(&SG[(r2 + rr) * S8 + c4], ld4(&SF[(r2 + rr) * S8 + c4]));
    if (tid < ZD) mus[tid] = muf[tid];
    __syncthreads();

    // ================= BACKWARD SMOOTHER =================
    for (int t = T_ - 2; t >= 0; t--) {
        // s0: mix A(t+1); load SF(t), muf(t) from out
        mixA(t + 1);
        {
            const float4* og4 = (const float4*)(osg + (size_t)t * ZD * ZD);
#pragma unroll
            for (int rr = 0; rr < 2; rr++)
                st4f(&SF[(r2 + rr) * S8 + c4], og4[(r2 + rr) * 16 + cg]);
        }
        if (tid >= 448) muf[tid - 448] = omu[t * ZD + (tid - 448)];
        __syncthreads();

        // s1: M = A(t+1) @ SF -> Mm (fat) ; mpn = A @ muf (wave 7)
        if (tid < 256) {
            float acc[4][4] = {};
            mm44<ZD, S8, S8, false>(Am, SF, acc, r4f, c4);
#pragma unroll
            for (int q = 0; q < 4; q++)
                st4f(&Mm[(r4f + q) * S8 + c4],
                     make_float4(acc[q][0], acc[q][1], acc[q][2], acc[q][3]));
        }
        if (tid >= 448) {
            const int i = tid - 448;
            float s = 0.f;
            const float* pa = Am + i * S8;
#pragma unroll 8
            for (int k = 0; k < ZD; k++) s += pa[k] * muf[k];
            mpn[i] = s;
        }
        __syncthreads();

        // s2: spn = M @ A^T + Q -> SP (fat) ; dv = mus - mpn (wave 7)
        if (tid < 256) {
            float acc[4][4] = {};
            mm44<ZD, S8, S8, false>(Mm, At, acc, r4f, c4);
#pragma unroll
            for (int q = 0; q < 4; q++) {
                const int r = r4f + q;
#pragma unroll
                for (int j = 0; j < 4; j++)
                    SP[r * S8 + c4 + j] = acc[q][j] + ((r == c4 + j) ? 0.08f : 0.0f);
            }
        }
        if (tid >= 448) { const int i = tid - 448; dv[i] = mus[i] - mpn[i]; }
        __syncthreads();

        // ---- GJ64 (4-wide pivots, 16 steps, 1 barrier each): [SP | Mm] -> Xb = spn^-1 M
        {
            float4 aL0 = ld4(&SP[gi * S8 + gs * 8]);
            float4 aL1 = ld4(&SP[gi * S8 + gs * 8 + 4]);
            float4 aR0 = ld4(&Mm[gi * S8 + gs * 8]);
            float4 aR1 = ld4(&Mm[gi * S8 + gs * 8 + 4]);
            if (gi < 4) {
                st4f(&pvL[gi * 64 + gs * 8], aL0); st4f(&pvL[gi * 64 + gs * 8 + 4], aL1);
                st4f(&pvR[gi * 64 + gs * 8], aR0); st4f(&pvR[gi * 64 + gs * 8 + 4], aR1);
            }
            if (gs == 0) st4f(&fbb[gi * 4], aL0);
            __syncthreads();

#pragma unroll 2
            for (int j = 0; j < 16; ++j) {
                const int par = j & 1, nb = par ^ 1;
                const bool isp = (gi >> 2) == j;
                const int i4 = gi & 3;
                const float4 q0 = ld4(&fbb[par * 256 + (4 * j + 0) * 4]);
                const float4 q1 = ld4(&fbb[par * 256 + (4 * j + 1) * 4]);
                const float4 q2 = ld4(&fbb[par * 256 + (4 * j + 2) * 4]);
                const float4 q3 = ld4(&fbb[par * 256 + (4 * j + 3) * 4]);
                float4 pi0, pi1, pi2, pi3;
                pinv4(q0, q1, q2, q3, pi0, pi1, pi2, pi3);
                float4 coef;
                if (isp) coef = (i4 == 0 ? pi0 : i4 == 1 ? pi1 : i4 == 2 ? pi2 : pi3);
                else {
                    const float4 f = ld4(&fbb[par * 256 + gi * 4]);
                    coef = comb4(f, pi0, pi1, pi2, pi3);
                }
                // left halves
                {
                    const float4 x0 = ld4(&pvL[par * 256 + 0 * 64 + gs * 8]);
                    const float4 x1 = ld4(&pvL[par * 256 + 1 * 64 + gs * 8]);
                    const float4 x2 = ld4(&pvL[par * 256 + 2 * 64 + gs * 8]);
                    const float4 x3 = ld4(&pvL[par * 256 + 3 * 64 + gs * 8]);
                    const float4 c = comb4(coef, x0, x1, x2, x3);
                    if (isp) aL0 = c;
                    else { aL0.x -= c.x; aL0.y -= c.y; aL0.z -= c.z; aL0.w -= c.w; }
                }
                {
                    const float4 x0 = ld4(&pvL[par * 256 + 0 * 64 + gs * 8 + 4]);
                    const float4 x1 = ld4(&pvL[par * 256 + 1 * 64 + gs * 8 + 4]);
                    const float4 x2 = ld4(&pvL[par * 256 + 2 * 64 + gs * 8 + 4]);
                    const float4 x3 = ld4(&pvL[par * 256 + 3 * 64 + gs * 8 + 4]);
                    const float4 c = comb4(coef, x0, x1, x2, x3);
                    if (isp) aL1 = c;
                    else { aL1.x -= c.x; aL1.y -= c.y; aL1.z -= c.z; aL1.w -= c.w; }
                }
                // right halves
                {
                    const float4 x0 = ld4(&pvR[par * 256 + 0 * 64 + gs * 8]);
                    const float4 x1 = ld4(&pvR[par * 256 + 1 * 64 + gs * 8]);
                    const float4 x2 = ld4(&pvR[par * 256 + 2 * 64 + gs * 8]);
                    const float4 x3 = ld4(&pvR[par * 256 + 3 * 64 + gs * 8]);
                    const float4 c = comb4(coef, x0, x1, x2, x3);
                    if (isp) aR0 = c;
                    else { aR0.x -= c.x; aR0.y -= c.y; aR0.z -= c.z; aR0.w -= c.w; }
                }
                {
                    const float4 x0 = ld4(&pvR[par * 256 + 0 * 64 + gs * 8 + 4]);
                    const float4 x1 = ld4(&pvR[par * 256 + 1 * 64 + gs * 8 + 4]);
                    const float4 x2 = ld4(&pvR[par * 256 + 2 * 64 + gs * 8 + 4]);
                    const float4 x3 = ld4(&pvR[par * 256 + 3 * 64 + gs * 8 + 4]);
                    const float4 c = comb4(coef, x0, x1, x2, x3);
                    if (isp) aR1 = c;
                    else { aR1.x -= c.x; aR1.y -= c.y; aR1.z -= c.z; aR1.w -= c.w; }
                }
                if (j < 15) {
                    if ((gi >> 2) == j + 1) {     // publish next pivot rows
                        const int rn = gi & 3;
                        st4f(&pvL[nb * 256 + rn * 64 + gs * 8], aL0);
                        st4f(&pvL[nb * 256 + rn * 64 + gs * 8 + 4], aL1);
                        st4f(&pvR[nb * 256 + rn * 64 + gs * 8], aR0);
                        st4f(&pvR[nb * 256 + rn * 64 + gs * 8 + 4], aR1);
                    }
                    if (gs == ((j + 1) >> 1))
                        st4f(&fbb[nb * 256 + gi * 4], ((j + 1) & 1) ? aL1 : aL0);
                }
                __syncthreads();
            }
            st4f(&Xb[gi * S8 + gs * 8], aR0);
            st4f(&Xb[gi * S8 + gs * 8 + 4], aR1);
        }
        __syncthreads();

        // s3: V = SG @ Xb - M -> SP (fat)
        if (tid < 256) {
            float acc[4][4] = {};
            mm44<ZD, S8, S8, false>(SG, Xb, acc, r4f, c4);
#pragma unroll
            for (int q = 0; q < 4; q++) {
                const int r = r4f + q;
                const float4 m = ld4(&Mm[r * S8 + c4]);
                SP[r * S8 + c4 + 0] = acc[q][0] - m.x;
                SP[r * S8 + c4 + 1] = acc[q][1] - m.y;
                SP[r * S8 + c4 + 2] = acc[q][2] - m.z;
                SP[r * S8 + c4 + 3] = acc[q][3] - m.w;
            }
        }
        __syncthreads();

        // s4: sig_s = SF + Xb^T @ SP -> SG & out (fat) ; mu_s = muf + Xb^T dv (wave 7)
        if (tid < 256) {
            float acc[4][4] = {};
            mm44<ZD, S8, S8, true>(Xb, SP, acc, r4f, c4);
            float* og = osg + (size_t)t * ZD * ZD;
#pragma unroll
            for (int q = 0; q < 4; q++) {
                const int r = r4f + q;
                const float4 sf = ld4(&SF[r * S8 + c4]);
                const float4 v = make_float4(sf.x + acc[q][0], sf.y + acc[q][1],
                                             sf.z + acc[q][2], sf.w + acc[q][3]);
                st4f(&SG[r * S8 + c4], v);
                *(float4*)(og + r * ZD + c4) = v;
            }
        }
        if (tid >= 448) {
            const int i = tid - 448;
            float s = 0.f;
#pragma unroll 8
            for (int k = 0; k < ZD; k++) s += Xb[k * S8 + i] * dv[k];
            const float v = muf[i] + s;
            mus[i] = v;
            omu[t * ZD + i] = v;
        }
        __syncthreads();
    }
}

extern "C" void kernel_launch(void* const* d_in, const int* in_sizes, int n_in,
                              void* d_out, int out_size, void* d_ws, size_t ws_size,
                              hipStream_t stream) {
    const float* obs = (const float*)d_in[0];
    const float* lg  = (const float*)d_in[1];
    const float* AK  = (const float*)d_in[2];
    const float* CK  = (const float*)d_in[3];
    (void)d_ws; (void)ws_size; (void)in_sizes; (void)n_in; (void)out_size;
    kvae_kernel<<<dim3(B_), dim3(512), 0, stream>>>(obs, lg, AK, CK, (float*)d_out);
}

// Round 13
// 3560.388 us; speedup vs baseline: 1.0701x; 1.0701x over previous
//
#include <hip/hip_runtime.h>

#define B_ 128
#define T_ 80
#define AD 32
#define ZD 64
#define KD 16
#define S8 68   // stride for 64-col LDS matrices (16B-aligned rows)
#define SC 36   // stride for 32-col matrices (16B-aligned rows)

__device__ __forceinline__ float4 ld4(const float* p) { return *(const float4*)p; }
__device__ __forceinline__ void st4f(float* p, float4 v) { *(float4*)p = v; }
__device__ __forceinline__ float4 sub4(float4 a, float4 b) {
    return make_float4(a.x - b.x, a.y - b.y, a.z - b.z, a.w - b.w);
}
// row-vector c times matrix given as rows x0..x3
__device__ __forceinline__ float4 comb4(float4 c, float4 x0, float4 x1, float4 x2, float4 x3) {
    return make_float4(c.x*x0.x + c.y*x1.x + c.z*x2.x + c.w*x3.x,
                       c.x*x0.y + c.y*x1.y + c.z*x2.y + c.w*x3.y,
                       c.x*x0.z + c.y*x1.z + c.z*x2.z + c.w*x3.z,
                       c.x*x0.w + c.y*x1.w + c.z*x2.w + c.w*x3.w);
}

// 4x4 inverse via 2x2-block Schur (SPD -> no pivoting). Returns rows of the inverse.
__device__ __forceinline__ void pinv4(float4 q0, float4 q1, float4 q2, float4 q3,
                                      float4& pi0, float4& pi1, float4& pi2, float4& pi3)
{
    const float ra = 1.0f / (q0.x*q1.y - q0.y*q1.x);
    const float ai00 =  q1.y*ra, ai01 = -q0.y*ra, ai10 = -q1.x*ra, ai11 = q0.x*ra;
    const float ca00 = q2.x*ai00 + q2.y*ai10, ca01 = q2.x*ai01 + q2.y*ai11;
    const float ca10 = q3.x*ai00 + q3.y*ai10, ca11 = q3.x*ai01 + q3.y*ai11;
    const float s00 = q2.z - (ca00*q0.z + ca01*q1.z), s01 = q2.w - (ca00*q0.w + ca01*q1.w);
    const float s10 = q3.z - (ca10*q0.z + ca11*q1.z), s11 = q3.w - (ca10*q0.w + ca11*q1.w);
    const float rs = 1.0f / (s00*s11 - s01*s10);
    const float si00 = s11*rs, si01 = -s01*rs, si10 = -s10*rs, si11 = s00*rs;
    const float ab00 = ai00*q0.z + ai01*q1.z, ab01 = ai00*q0.w + ai01*q1.w;
    const float ab10 = ai10*q0.z + ai11*q1.z, ab11 = ai10*q0.w + ai11*q1.w;
    const float t00 = ab00*si00 + ab01*si10, t01 = ab00*si01 + ab01*si11;
    const float t10 = ab10*si00 + ab11*si10, t11 = ab10*si01 + ab11*si11;
    const float tl00 = ai00 + (t00*ca00 + t01*ca10), tl01 = ai01 + (t00*ca01 + t01*ca11);
    const float tl10 = ai10 + (t10*ca00 + t11*ca10), tl11 = ai11 + (t10*ca01 + t11*ca11);
    const float bl00 = -(si00*ca00 + si01*ca10), bl01 = -(si00*ca01 + si01*ca11);
    const float bl10 = -(si10*ca00 + si11*ca10), bl11 = -(si10*ca01 + si11*ca11);
    pi0 = make_float4(tl00, tl01, -t00, -t01);
    pi1 = make_float4(tl10, tl11, -t10, -t11);
    pi2 = make_float4(bl00, bl01, si00, si01);
    pi3 = make_float4(bl10, bl11, si10, si11);
}

// acc[2][4] += op(Pa) @ Qb for rows (r2,r2+1), cols c4..c4+3.
template<int KL, int AS, int BS, bool ATRANS>
__device__ __forceinline__ void mm64(const float* __restrict__ Pa, const float* __restrict__ Qb,
                                     float acc[2][4], int r2, int c4)
{
#pragma unroll 8
    for (int k = 0; k < KL; k++) {
        float aA, aB;
        if (ATRANS) { aA = Pa[k * AS + r2];   aB = Pa[k * AS + r2 + 1]; }
        else        { aA = Pa[r2 * AS + k];   aB = Pa[(r2 + 1) * AS + k]; }
        const float4 bv = ld4(&Qb[k * BS + c4]);
        acc[0][0] += aA * bv.x; acc[0][1] += aA * bv.y; acc[0][2] += aA * bv.z; acc[0][3] += aA * bv.w;
        acc[1][0] += aB * bv.x; acc[1][1] += aB * bv.y; acc[1][2] += aB * bv.z; acc[1][3] += aB * bv.w;
    }
}

__global__ __launch_bounds__(512, 2)
void kvae_kernel(const float* __restrict__ obs, const float* __restrict__ logits,
                 const float* __restrict__ AK, const float* __restrict__ CK,
                 float* __restrict__ out)
{
    __shared__ __align__(16) float W[T_ * KD];
    __shared__ __align__(16) float Am[ZD * S8];   // A(t+1)
    __shared__ __align__(16) float At[ZD * S8];   // A(t+1)^T
    __shared__ __align__(16) float SP[ZD * S8];   // sig_p / spn / V
    __shared__ __align__(16) float SF[ZD * S8];   // sig_f
    __shared__ __align__(16) float Mm[ZD * S8];   // M
    __shared__ __align__(16) float Pool[9984];
    __shared__ __align__(16) float pvL[512];      // published pivot rows, left
    __shared__ __align__(16) float pvR[512];      // published pivot rows, right
    __shared__ __align__(16) float fbb[512];      // per-row multiplier quads
    __shared__ __align__(16) float pvE[8];        // err col pivot values [2][4]
    __shared__ __align__(16) float y_s[32];
    __shared__ __align__(16) float errv[32];
    __shared__ __align__(16) float uev[32];
    __shared__ __align__(16) float mup[64];
    __shared__ __align__(16) float muf[64];
    __shared__ __align__(16) float mus[64];
    __shared__ __align__(16) float mpn[64];
    __shared__ __align__(16) float dv[64];

    // forward aliases
    float* T1 = Pool;            // [32][68]
    float* CM = Pool + 2176;     // [32][68]
    float* CT = Pool + 4352;     // [64][36]  C^T
    float* U_ = Pool + 6656;     // [32][68]  S^-1 T1
    float* S_ = Pool + 8832;     // [32][36]
    // backward aliases
    float* Xb = Pool;            // [64][68]  X = spn^-1 M
    float* SG = Pool + 4352;     // [64][68]  sig_s carry

    const int tid = threadIdx.x;
    const int b   = blockIdx.x;

    const int r16 = tid >> 4;       // 0..31
    const int cg  = tid & 15;       // 0..15
    const int c4  = cg << 2;        // 0..60
    const int c2  = cg << 1;        // 0..30
    const int r2  = r16 << 1;       // 0..62
    const int gi  = tid >> 3;       // 0..63  GJ64 row
    const int gs  = tid & 7;        // 0..7   GJ64 seg (8 cols)

    const float* obs_b = obs    + (size_t)b * T_ * AD;
    const float* lg_b  = logits + (size_t)b * T_ * KD;
    float* omu = out + (size_t)b * T_ * ZD;
    float* osg = out + (size_t)B_ * T_ * ZD + (size_t)b * T_ * ZD * ZD;
    const float4* AK4 = (const float4*)AK;
    const float4* CK4 = (const float4*)CK;

    auto mixA = [&](int tt) {
#pragma unroll
        for (int rr = 0; rr < 2; rr++) {
            const int r = r2 + rr;
            float4 a = make_float4(0.f, 0.f, 0.f, 0.f);
#pragma unroll
            for (int k = 0; k < KD; k++) {
                const float wk = W[tt * KD + k];
                const float4 v = AK4[k * 1024 + r * 16 + cg];
                a.x += wk * v.x; a.y += wk * v.y; a.z += wk * v.z; a.w += wk * v.w;
            }
            st4f(&Am[r * S8 + c4], a);
            At[(c4 + 0) * S8 + r] = a.x; At[(c4 + 1) * S8 + r] = a.y;
            At[(c4 + 2) * S8 + r] = a.z; At[(c4 + 3) * S8 + r] = a.w;
        }
    };
    auto mixC = [&](int tt) {
        float4 a = make_float4(0.f, 0.f, 0.f, 0.f);
#pragma unroll
        for (int k = 0; k < KD; k++) {
            const float wk = W[tt * KD + k];
            const float4 v = CK4[k * 512 + r16 * 16 + cg];
            a.x += wk * v.x; a.y += wk * v.y; a.z += wk * v.z; a.w += wk * v.w;
        }
        st4f(&CM[r16 * S8 + c4], a);
        CT[(c4 + 0) * SC + r16] = a.x; CT[(c4 + 1) * SC + r16] = a.y;
        CT[(c4 + 2) * SC + r16] = a.z; CT[(c4 + 3) * SC + r16] = a.w;
    };

    // ---- prologue
    if (tid < T_) {
        float l[KD]; float mx = -1e30f;
#pragma unroll
        for (int k = 0; k < KD; k++) { l[k] = lg_b[tid * KD + k]; mx = fmaxf(mx, l[k]); }
        float s = 0.f;
#pragma unroll
        for (int k = 0; k < KD; k++) { l[k] = expf(l[k] - mx); s += l[k]; }
        const float inv = 1.0f / s;
#pragma unroll
        for (int k = 0; k < KD; k++) W[tid * KD + k] = l[k] * inv;
    }
#pragma unroll
    for (int rr = 0; rr < 2; rr++) {
        const int r = r2 + rr;
#pragma unroll
        for (int j = 0; j < 4; j++) SP[r * S8 + c4 + j] = (r == c4 + j) ? 20.0f : 0.0f;
    }
    if (tid < ZD) mup[tid] = 0.0f;
    __syncthreads();

    // ================= FORWARD FILTER =================
    for (int t = 0; t < T_; t++) {
        // s0: mix A(t+1), C(t); load y
        if (t < T_ - 1) mixA(t + 1);
        mixC(t);
        if (tid < AD) y_s[tid] = obs_b[t * AD + tid];
        __syncthreads();

        // s1+s2 fused (wave-synchronous: S row r16 reads T1 row r16, written by the
        // SAME wave's 16 lanes — DS ops from one wave complete in order, no barrier)
        // s1: T1 = CM @ SP  [32x64] k=64
        {
            float a0 = 0, a1 = 0, a2 = 0, a3 = 0;
            const float* pa = CM + r16 * S8;
#pragma unroll 8
            for (int k = 0; k < ZD; k++) {
                const float a = pa[k];
                const float4 bv = ld4(&SP[k * S8 + c4]);
                a0 += a * bv.x; a1 += a * bv.y; a2 += a * bv.z; a3 += a * bv.w;
            }
            T1[r16 * S8 + c4 + 0] = a0; T1[r16 * S8 + c4 + 1] = a1;
            T1[r16 * S8 + c4 + 2] = a2; T1[r16 * S8 + c4 + 3] = a3;
        }
        // s2: S = T1 @ CT + 0.03 I ; errv = y - CM @ mup
        {
            float a0 = 0, a1 = 0;
            const float* pa = T1 + r16 * S8;
#pragma unroll 8
            for (int k = 0; k < ZD; k++) {
                const float a = pa[k];
                const float2 bv = *(const float2*)&CT[k * SC + c2];
                a0 += a * bv.x; a1 += a * bv.y;
            }
            if (r16 == c2)     a0 += 0.03f;
            if (r16 == c2 + 1) a1 += 0.03f;
            S_[r16 * SC + c2] = a0; S_[r16 * SC + c2 + 1] = a1;
        }
        if (tid < AD) {
            float s = 0.f;
#pragma unroll
            for (int k4 = 0; k4 < ZD; k4 += 4) {
                const float4 cm = ld4(&CM[tid * S8 + k4]);
                const float4 mu = ld4(&mup[k4]);
                s += cm.x*mu.x + cm.y*mu.y + cm.z*mu.z + cm.w*mu.w;
            }
            errv[tid] = y_s[tid] - s;
        }
        __syncthreads();

        // ---- GJ32 (4-wide pivots, 8 steps): [S_ | T1, errv] -> U_, uev
        {
            const int hi = r16, hs = cg;
            float4 aL = make_float4(0, 0, 0, 0);
            float4 aR = ld4(&T1[hi * S8 + hs * 4]);
            float e = 0.f;
            if (hs < 8) aL = ld4(&S_[hi * SC + hs * 4]);
            if (hs == 15) e = errv[hi];
            if (hi < 4) {
                if (hs < 8) st4f(&pvL[hi * 32 + hs * 4], aL);        // pvL fwd: [2][4][32]
                st4f(&pvR[hi * 64 + hs * 4], aR);
                if (hs == 15) pvE[hi] = e;
            }
            if (hs == 0) st4f(&fbb[hi * 4], aL);                     // fbb fwd: [2][32][4]
            __syncthreads();

#pragma unroll 2
            for (int j = 0; j < 8; ++j) {
                const int par = j & 1, nb = par ^ 1;
                const bool isp = (hi >> 2) == j;
                const int i4 = hi & 3;
                const float4 q0 = ld4(&fbb[par * 128 + (4 * j + 0) * 4]);
                const float4 q1 = ld4(&fbb[par * 128 + (4 * j + 1) * 4]);
                const float4 q2 = ld4(&fbb[par * 128 + (4 * j + 2) * 4]);
                const float4 q3 = ld4(&fbb[par * 128 + (4 * j + 3) * 4]);
                float4 pi0, pi1, pi2, pi3;
                pinv4(q0, q1, q2, q3, pi0, pi1, pi2, pi3);
                float4 coef;
                if (isp) coef = (i4 == 0 ? pi0 : i4 == 1 ? pi1 : i4 == 2 ? pi2 : pi3);
                else {
                    const float4 f = ld4(&fbb[par * 128 + hi * 4]);
                    coef = comb4(f, pi0, pi1, pi2, pi3);
                }
                // right (always live)
                {
                    const float4 c = comb4(coef,
                        ld4(&pvR[par * 256 + 0 * 64 + hs * 4]),
                        ld4(&pvR[par * 256 + 1 * 64 + hs * 4]),
                        ld4(&pvR[par * 256 + 2 * 64 + hs * 4]),
                        ld4(&pvR[par * 256 + 3 * 64 + hs * 4]));
                    if (isp) aR = c; else aR = sub4(aR, c);
                }
                // left
                if (hs < 8) {
                    const float4 c = comb4(coef,
                        ld4(&pvL[par * 128 + 0 * 32 + hs * 4]),
                        ld4(&pvL[par * 128 + 1 * 32 + hs * 4]),
                        ld4(&pvL[par * 128 + 2 * 32 + hs * 4]),
                        ld4(&pvL[par * 128 + 3 * 32 + hs * 4]));
                    if (isp) aL = c; else aL = sub4(aL, c);
                }
                // err
                if (hs == 15) {
                    const float4 ev = ld4(&pvE[par * 4]);
                    const float ce = coef.x*ev.x + coef.y*ev.y + coef.z*ev.z + coef.w*ev.w;
                    if (isp) e = ce; else e -= ce;
                }
                if (j < 7) {
                    if ((hi >> 2) == j + 1) {   // publish next pivot rows
                        if (hs < 8) st4f(&pvL[nb * 128 + i4 * 32 + hs * 4], aL);
                        st4f(&pvR[nb * 256 + i4 * 64 + hs * 4], aR);
                        if (hs == 15) pvE[nb * 4 + i4] = e;
                    }
                    if (hs == j + 1) st4f(&fbb[nb * 128 + hi * 4], aL);
                }
                __syncthreads();
            }
            st4f(&U_[hi * S8 + hs * 4], aR);
            if (hs == 15) uev[hi] = e;
        }
        __syncthreads();

        // s3: sig_f = SP - T1^T U_ -> SF & out ; mu_f = mup + T1^T uev
        {
            float acc[2][4] = {};
            mm64<AD, S8, S8, true>(T1, U_, acc, r2, c4);
            float* og = osg + (size_t)t * ZD * ZD;
#pragma unroll
            for (int rr = 0; rr < 2; rr++) {
                const int r = r2 + rr;
                const float4 sp = ld4(&SP[r * S8 + c4]);
                const float4 v = make_float4(sp.x - acc[rr][0], sp.y - acc[rr][1],
                                             sp.z - acc[rr][2], sp.w - acc[rr][3]);
                st4f(&SF[r * S8 + c4], v);
                *(float4*)(og + r * ZD + c4) = v;
            }
        }
        if (tid < ZD) {
            float s = 0.f;
#pragma unroll
            for (int k = 0; k < AD; k++) s += T1[k * S8 + tid] * uev[k];
            const float v = mup[tid] + s;
            muf[tid] = v;
            omu[t * ZD + tid] = v;
        }
        __syncthreads();

        if (t < T_ - 1) {
            // s4+s5 fused (SP' row r2 reads Mm rows r2,r2+1 — same wave's lanes)
            // s4: M = A(t+1) @ SF
            {
                float acc[2][4] = {};
                mm64<ZD, S8, S8, false>(Am, SF, acc, r2, c4);
#pragma unroll
                for (int rr = 0; rr < 2; rr++)
                    st4f(&Mm[(r2 + rr) * S8 + c4],
                         make_float4(acc[rr][0], acc[rr][1], acc[rr][2], acc[rr][3]));
            }
            // s5: SP' = M @ A^T + Q ; mup' = A(t+1) @ muf
            {
                float acc[2][4] = {};
                mm64<ZD, S8, S8, false>(Mm, At, acc, r2, c4);
#pragma unroll
                for (int rr = 0; rr < 2; rr++) {
                    const int r = r2 + rr;
#pragma unroll
                    for (int j = 0; j < 4; j++)
                        SP[r * S8 + c4 + j] = acc[rr][j] + ((r == c4 + j) ? 0.08f : 0.0f);
                }
            }
            if (tid >= 448) {
                const int i = tid - 448;
                float s = 0.f;
                const float* pa = Am + i * S8;
#pragma unroll 8
                for (int k = 0; k < ZD; k++) s += pa[k] * muf[k];
                mup[i] = s;
            }
            __syncthreads();
        }
    }

    // ================= SMOOTHER INIT =================
#pragma unroll
    for (int rr = 0; rr < 2; rr++)
        st4f(&SG[(r2 + rr) * S8 + c4], ld4(&SF[(r2 + rr) * S8 + c4]));
    if (tid < ZD) mus[tid] = muf[tid];
    __syncthreads();

    // ================= BACKWARD SMOOTHER =================
    for (int t = T_ - 2; t >= 0; t--) {
        // s0: mix A(t+1); load SF(t), muf(t) from out
        mixA(t + 1);
        {
            const float4* og4 = (const float4*)(osg + (size_t)t * ZD * ZD);
#pragma unroll
            for (int rr = 0; rr < 2; rr++)
                st4f(&SF[(r2 + rr) * S8 + c4], og4[(r2 + rr) * 16 + cg]);
        }
        if (tid >= 448) muf[tid - 448] = omu[t * ZD + (tid - 448)];
        __syncthreads();

        // s1+s2 fused (spn row r2 reads Mm rows r2,r2+1 — same wave's lanes)
        // s1: M = A(t+1) @ SF -> Mm ; mpn = A @ muf
        {
            float acc[2][4] = {};
            mm64<ZD, S8, S8, false>(Am, SF, acc, r2, c4);
#pragma unroll
            for (int rr = 0; rr < 2; rr++)
                st4f(&Mm[(r2 + rr) * S8 + c4],
                     make_float4(acc[rr][0], acc[rr][1], acc[rr][2], acc[rr][3]));
        }
        // s2: spn = M @ A^T + Q -> SP ; dv = mus - mpn (wave 7: mpn then dv in-register)
        {
            float acc[2][4] = {};
            mm64<ZD, S8, S8, false>(Mm, At, acc, r2, c4);
#pragma unroll
            for (int rr = 0; rr < 2; rr++) {
                const int r = r2 + rr;
#pragma unroll
                for (int j = 0; j < 4; j++)
                    SP[r * S8 + c4 + j] = acc[rr][j] + ((r == c4 + j) ? 0.08f : 0.0f);
            }
        }
        if (tid >= 448) {
            const int i = tid - 448;
            float s = 0.f;
            const float* pa = Am + i * S8;
#pragma unroll 8
            for (int k = 0; k < ZD; k++) s += pa[k] * muf[k];
            mpn[i] = s;
            dv[i] = mus[i] - s;
        }
        __syncthreads();

        // ---- GJ64 (4-wide pivots, 16 steps, 1 barrier each): [SP | Mm] -> Xb = spn^-1 M
        {
            float4 aL0 = ld4(&SP[gi * S8 + gs * 8]);
            float4 aL1 = ld4(&SP[gi * S8 + gs * 8 + 4]);
            float4 aR0 = ld4(&Mm[gi * S8 + gs * 8]);
            float4 aR1 = ld4(&Mm[gi * S8 + gs * 8 + 4]);
            if (gi < 4) {
                st4f(&pvL[gi * 64 + gs * 8], aL0); st4f(&pvL[gi * 64 + gs * 8 + 4], aL1);
                st4f(&pvR[gi * 64 + gs * 8], aR0); st4f(&pvR[gi * 64 + gs * 8 + 4], aR1);
            }
            if (gs == 0) st4f(&fbb[gi * 4], aL0);
            __syncthreads();

#pragma unroll 2
            for (int j = 0; j < 16; ++j) {
                const int par = j & 1, nb = par ^ 1;
                const bool isp = (gi >> 2) == j;
                const int i4 = gi & 3;
                const float4 q0 = ld4(&fbb[par * 256 + (4 * j + 0) * 4]);
                const float4 q1 = ld4(&fbb[par * 256 + (4 * j + 1) * 4]);
                const float4 q2 = ld4(&fbb[par * 256 + (4 * j + 2) * 4]);
                const float4 q3 = ld4(&fbb[par * 256 + (4 * j + 3) * 4]);
                float4 pi0, pi1, pi2, pi3;
                pinv4(q0, q1, q2, q3, pi0, pi1, pi2, pi3);
                float4 coef;
                if (isp) coef = (i4 == 0 ? pi0 : i4 == 1 ? pi1 : i4 == 2 ? pi2 : pi3);
                else {
                    const float4 f = ld4(&fbb[par * 256 + gi * 4]);
                    coef = comb4(f, pi0, pi1, pi2, pi3);
                }
                // left halves
                {
                    const float4 x0 = ld4(&pvL[par * 256 + 0 * 64 + gs * 8]);
                    const float4 x1 = ld4(&pvL[par * 256 + 1 * 64 + gs * 8]);
                    const float4 x2 = ld4(&pvL[par * 256 + 2 * 64 + gs * 8]);
                    const float4 x3 = ld4(&pvL[par * 256 + 3 * 64 + gs * 8]);
                    const float4 c = comb4(coef, x0, x1, x2, x3);
                    if (isp) aL0 = c;
                    else { aL0.x -= c.x; aL0.y -= c.y; aL0.z -= c.z; aL0.w -= c.w; }
                }
                {
                    const float4 x0 = ld4(&pvL[par * 256 + 0 * 64 + gs * 8 + 4]);
                    const float4 x1 = ld4(&pvL[par * 256 + 1 * 64 + gs * 8 + 4]);
                    const float4 x2 = ld4(&pvL[par * 256 + 2 * 64 + gs * 8 + 4]);
                    const float4 x3 = ld4(&pvL[par * 256 + 3 * 64 + gs * 8 + 4]);
                    const float4 c = comb4(coef, x0, x1, x2, x3);
                    if (isp) aL1 = c;
                    else { aL1.x -= c.x; aL1.y -= c.y; aL1.z -= c.z; aL1.w -= c.w; }
                }
                // right halves
                {
                    const float4 x0 = ld4(&pvR[par * 256 + 0 * 64 + gs * 8]);
                    const float4 x1 = ld4(&pvR[par * 256 + 1 * 64 + gs * 8]);
                    const float4 x2 = ld4(&pvR[par * 256 + 2 * 64 + gs * 8]);
                    const float4 x3 = ld4(&pvR[par * 256 + 3 * 64 + gs * 8]);
                    const float4 c = comb4(coef, x0, x1, x2, x3);
                    if (isp) aR0 = c;
                    else { aR0.x -= c.x; aR0.y -= c.y; aR0.z -= c.z; aR0.w -= c.w; }
                }
                {
                    const float4 x0 = ld4(&pvR[par * 256 + 0 * 64 + gs * 8 + 4]);
                    const float4 x1 = ld4(&pvR[par * 256 + 1 * 64 + gs * 8 + 4]);
                    const float4 x2 = ld4(&pvR[par * 256 + 2 * 64 + gs * 8 + 4]);
                    const float4 x3 = ld4(&pvR[par * 256 + 3 * 64 + gs * 8 + 4]);
                    const float4 c = comb4(coef, x0, x1, x2, x3);
                    if (isp) aR1 = c;
                    else { aR1.x -= c.x; aR1.y -= c.y; aR1.z -= c.z; aR1.w -= c.w; }
                }
                if (j < 15) {
                    if ((gi >> 2) == j + 1) {     // publish next pivot rows
                        const int rn = gi & 3;
                        st4f(&pvL[nb * 256 + rn * 64 + gs * 8], aL0);
                        st4f(&pvL[nb * 256 + rn * 64 + gs * 8 + 4], aL1);
                        st4f(&pvR[nb * 256 + rn * 64 + gs * 8], aR0);
                        st4f(&pvR[nb * 256 + rn * 64 + gs * 8 + 4], aR1);
                    }
                    if (gs == ((j + 1) >> 1))
                        st4f(&fbb[nb * 256 + gi * 4], ((j + 1) & 1) ? aL1 : aL0);
                }
                __syncthreads();
            }
            st4f(&Xb[gi * S8 + gs * 8], aR0);
            st4f(&Xb[gi * S8 + gs * 8 + 4], aR1);
        }
        __syncthreads();

        // s3: V = SG @ Xb - M -> SP
        {
            float acc[2][4] = {};
            mm64<ZD, S8, S8, false>(SG, Xb, acc, r2, c4);
#pragma unroll
            for (int rr = 0; rr < 2; rr++) {
                const int r = r2 + rr;
                const float4 m = ld4(&Mm[r * S8 + c4]);
                SP[r * S8 + c4 + 0] = acc[rr][0] - m.x;
                SP[r * S8 + c4 + 1] = acc[rr][1] - m.y;
                SP[r * S8 + c4 + 2] = acc[rr][2] - m.z;
                SP[r * S8 + c4 + 3] = acc[rr][3] - m.w;
            }
        }
        __syncthreads();

        // s4: sig_s = SF + Xb^T @ SP -> SG & out ; mu_s = muf + Xb^T dv
        {
            float acc[2][4] = {};
            mm64<ZD, S8, S8, true>(Xb, SP, acc, r2, c4);
            float* og = osg + (size_t)t * ZD * ZD;
#pragma unroll
            for (int rr = 0; rr < 2; rr++) {
                const int r = r2 + rr;
                const float4 sf = ld4(&SF[r * S8 + c4]);
                const float4 v = make_float4(sf.x + acc[rr][0], sf.y + acc[rr][1],
                                             sf.z + acc[rr][2], sf.w + acc[rr][3]);
                st4f(&SG[r * S8 + c4], v);
                *(float4*)(og + r * ZD + c4) = v;
            }
        }
        if (tid < ZD) {
            float s = 0.f;
#pragma unroll 8
            for (int k = 0; k < ZD; k++) s += Xb[k * S8 + tid] * dv[k];
            const float v = muf[tid] + s;
            mus[tid] = v;
            omu[t * ZD + tid] = v;
        }
        __syncthreads();
    }
}

extern "C" void kernel_launch(void* const* d_in, const int* in_sizes, int n_in,
                              void* d_out, int out_size, void* d_ws, size_t ws_size,
                              hipStream_t stream) {
    const float* obs = (const float*)d_in[0];
    const float* lg  = (const float*)d_in[1];
    const float* AK  = (const float*)d_in[2];
    const float* CK  = (const float*)d_in[3];
    (void)d_ws; (void)ws_size; (void)in_sizes; (void)n_in; (void)out_size;
    kvae_kernel<<<dim3(B_), dim3(512), 0, stream>>>(obs, lg, AK, CK, (float*)d_out);
}